// Round 8
// baseline (589.159 us; speedup 1.0000x reference)
//
#include <hip/hip_runtime.h>
#include <math.h>

#define DIM       4096
#define NKVH      8
#define HD        128
#define MAX_SEQ   4096
#define START_POS 4080
#define NQKV      6144
#define NCHUNK    8
#define CHUNK     512
#define ATT_SCALE 0.08838834764831845f

// ---- workspace layout (float offsets) ----
#define WS_PARTO  0           // 512*64*128 = 4194304
#define WS_QH     6291456     // 262144 fl = 524288 ushorts
#define WS_QL     6553600
#define WS_KNEW   6815744     // 131072
#define WS_VNEW   6946816     // 131072
#define WS_PM     7077888     // 32768
#define WS_PL     7110656     // 32768
#define WS_ATH    7143424     // 262144
#define WS_ATL    7405568     // 262144
#define WS_XH     7667712     // 262144
#define WS_XL     7929856     // 262144
// total = 8192000 floats = 32.8 MB

typedef __bf16 bf16x8 __attribute__((ext_vector_type(8)));
typedef float  f32x4  __attribute__((ext_vector_type(4)));
typedef unsigned int uintx4 __attribute__((ext_vector_type(4)));

__device__ __forceinline__ unsigned short f2bf(float f) {
    // native RTNE conversion
    return __builtin_bit_cast(unsigned short, (__bf16)f);
}
__device__ __forceinline__ float bf2f(unsigned short h) {
    union { unsigned int u; float f; } v; v.u = ((unsigned int)h) << 16;
    return v.f;
}
__device__ __forceinline__ void splitbf(float f, unsigned short &h, unsigned short &l) {
    h = f2bf(f);
    l = f2bf(f - bf2f(h));
}
__device__ __forceinline__ bf16x8 ldsfrag(const unsigned short* p) {
    uintx4 u = *(const uintx4*)p;
    return __builtin_bit_cast(bf16x8, u);
}
// 8B-aligned fragment load (two b64 reads) for rows whose stride is 8-mod-16 bytes
__device__ __forceinline__ bf16x8 ldsfrag2(const unsigned short* p) {
    union { uint2 u2[2]; bf16x8 v; } u;
    u.u2[0] = *(const uint2*)p;
    u.u2[1] = *(const uint2*)(p + 4);
    return u.v;
}
#define MFMA16(a,b,c) __builtin_amdgcn_mfma_f32_16x16x32_bf16(a, b, c, 0, 0, 0)
#define VCOMP(v,j) ((j)==0?(v).x:((j)==1?(v).y:((j)==2?(v).z:(v).w)))

// ---------------- split x -> bf16 hi/lo (float4 vectorized) ----------------
__global__ __launch_bounds__(256) void split_x_kernel(
    const float* __restrict__ x, unsigned short* __restrict__ xh,
    unsigned short* __restrict__ xl, int n4)
{
    int i = blockIdx.x * 256 + threadIdx.x;      // float4 index
    if (i < n4) {
        float4 v = *(const float4*)(x + (size_t)i * 4);
        ushort4 h, l;
        splitbf(v.x, h.x, l.x);
        splitbf(v.y, h.y, l.y);
        splitbf(v.z, h.z, l.z);
        splitbf(v.w, h.w, l.w);
        *(ushort4*)(xh + (size_t)i * 4) = h;
        *(ushort4*)(xl + (size_t)i * 4) = l;
    }
}

// ---------------- direct GEMM (no split-K): A = split-bf16, B = W fp32 -> bf16 ----------------
// r7 post-mortem: split-K's part round-trip (84MB) + 2 reduce kernels + launch gaps are
// the untested non-attn overhead. Direct K=4096 loop (64 iters of BK=64), bias + output
// conversion fused into the epilogue. M=32 x BN=128 per block -> qkv 192 blocks,
// oproj 128 blocks. Inner loop structure = r0's proven 2-barrier pattern.
// 256 thr / 4 waves: wave w -> (wm = w&1: m-tile of 16 rows, wn = w>>1: n-half of 64).
__device__ __forceinline__ void gemm_direct_loop(
    const unsigned short* __restrict__ Ah, const unsigned short* __restrict__ Al,
    const float* __restrict__ W, int ldW, int noff, int mrow0,
    unsigned short* Ahs, unsigned short* Als, unsigned short* Bs,
    f32x4 (&acc)[4])
{
    const int t = threadIdx.x;
    const int w = t >> 6, lane = t & 63, l15 = lane & 15, quad = lane >> 4;
    const int wm = w & 1, wn = w >> 1;
    #pragma unroll
    for (int nt = 0; nt < 4; ++nt) acc[nt] = (f32x4){0.f, 0.f, 0.f, 0.f};

    const int arow = t >> 3, ac0 = (t & 7) << 3;   // A tile 32x64 = 256 x8-vectors
    const int n4 = t & 31, kk = t >> 5;            // W tile 64x128 = 2048 float4

    uintx4 areg_h, areg_l;
    float4 wreg[8];
    auto LOAD = [&](int it) {
        int k0 = it * 64;
        size_t aoff = (size_t)(mrow0 + arow) * DIM + k0 + ac0;
        areg_h = *(const uintx4*)(Ah + aoff);
        areg_l = *(const uintx4*)(Al + aoff);
        #pragma unroll
        for (int i = 0; i < 8; ++i)
            wreg[i] = *(const float4*)(W + (size_t)(k0 + kk + 8 * i) * ldW + noff + n4 * 4);
    };

    LOAD(0);
    for (int it = 0; it < 64; ++it) {
        __syncthreads();
        *(uintx4*)(Ahs + arow * 72 + ac0) = areg_h;
        *(uintx4*)(Als + arow * 72 + ac0) = areg_l;
        #pragma unroll
        for (int i = 0; i < 8; ++i)
            #pragma unroll
            for (int j = 0; j < 4; ++j)
                Bs[(n4 * 4 + j) * 68 + kk + 8 * i] = f2bf(VCOMP(wreg[i], j));   // [n][k]
        __syncthreads();
        if (it < 63) LOAD(it + 1);               // in flight across MFMA phase
        #pragma unroll
        for (int kt = 0; kt < 2; ++kt) {
            int ko = kt * 32 + quad * 8;
            bf16x8 ah = ldsfrag(Ahs + (wm * 16 + l15) * 72 + ko);
            bf16x8 al = ldsfrag(Als + (wm * 16 + l15) * 72 + ko);
            #pragma unroll
            for (int nt = 0; nt < 4; ++nt) {
                bf16x8 b = ldsfrag2(Bs + ((wn * 4 + nt) * 16 + l15) * 68 + ko);
                acc[nt] = MFMA16(ah, b, acc[nt]);
                acc[nt] = MFMA16(al, b, acc[nt]);
            }
        }
    }
}

__global__ __launch_bounds__(256) void qkv_gemm_direct_kernel(
    const unsigned short* __restrict__ xh, const unsigned short* __restrict__ xl,
    const float* __restrict__ Wq, const float* __restrict__ Wk,
    const float* __restrict__ Wv,
    const float* __restrict__ bq, const float* __restrict__ bk,
    const float* __restrict__ bv,
    unsigned short* __restrict__ qh, unsigned short* __restrict__ ql,
    float* __restrict__ k_new, float* __restrict__ v_new)
{
    __shared__ unsigned short Ahs[32 * 72], Als[32 * 72], Bs[128 * 68];
    int ncol0 = blockIdx.x * 128;     // 0..6143; segments are 128-aligned
    int mrow0 = blockIdx.y * 32;
    const float* W; int ldW, noff;
    if (ncol0 < 4096)      { W = Wq; ldW = 4096; noff = ncol0; }
    else if (ncol0 < 5120) { W = Wk; ldW = 1024; noff = ncol0 - 4096; }
    else                   { W = Wv; ldW = 1024; noff = ncol0 - 5120; }

    f32x4 acc[4];
    gemm_direct_loop(xh, xl, W, ldW, noff, mrow0, Ahs, Als, Bs, acc);

    const int t = threadIdx.x;
    const int w = t >> 6, lane = t & 63, l15 = lane & 15, quad = lane >> 4;
    const int wm = w & 1, wn = w >> 1;
    #pragma unroll
    for (int nt = 0; nt < 4; ++nt)
        #pragma unroll
        for (int r = 0; r < 4; ++r) {
            int row = mrow0 + wm * 16 + quad * 4 + r;        // C/D: row=quad*4+reg
            int col = ncol0 + (wn * 4 + nt) * 16 + l15;      //      col=lane&15
            float v = acc[nt][r];
            if (col < 4096) {
                float q = v + bq[col];
                unsigned short h, l; splitbf(q, h, l);
                qh[row * 4096 + col] = h;
                ql[row * 4096 + col] = l;
            } else if (col < 5120) {
                k_new[row * 1024 + (col - 4096)] = v + bk[col - 4096];
            } else {
                v_new[row * 1024 + (col - 5120)] = v + bv[col - 5120];
            }
        }
}

__global__ __launch_bounds__(256) void oproj_gemm_direct_kernel(
    const unsigned short* __restrict__ ah, const unsigned short* __restrict__ al,
    const float* __restrict__ Wo, const float* __restrict__ bo,
    float* __restrict__ out)
{
    __shared__ unsigned short Ahs[32 * 72], Als[32 * 72], Bs[128 * 68];
    int ncol0 = blockIdx.x * 128;
    int mrow0 = blockIdx.y * 32;

    f32x4 acc[4];
    gemm_direct_loop(ah, al, Wo, 4096, ncol0, mrow0, Ahs, Als, Bs, acc);

    const int t = threadIdx.x;
    const int w = t >> 6, lane = t & 63, l15 = lane & 15, quad = lane >> 4;
    const int wm = w & 1, wn = w >> 1;
    #pragma unroll
    for (int nt = 0; nt < 4; ++nt)
        #pragma unroll
        for (int r = 0; r < 4; ++r) {
            int row = mrow0 + wm * 16 + quad * 4 + r;
            int col = ncol0 + (wn * 4 + nt) * 16 + l15;
            out[(size_t)row * 4096 + col] = acc[nt][r] + bo[col];
        }
}

// ---------------- MFMA flash-decoding attention (bf16 K/V/P, split-bf16 Q) ----------------
// r7 structure verbatim (at the measured ~3.25 TB/s pattern-bandwidth cap).
// 64-pos K/V tiles (8 iters), 1KB granule: block = (b*4 + gg)*8 + chunk(512 pos).
// pos-slot permutation pi(pos) = (pos&7)*8 + (pos>>3), applied to BOTH P and V^T.
__global__ __launch_bounds__(512, 2) void attn_partial7_kernel(
    const unsigned short* __restrict__ qhp, const unsigned short* __restrict__ qlp,
    const float* __restrict__ kc, const float* __restrict__ vc,
    const float* __restrict__ knew, const float* __restrict__ vnew,
    float* __restrict__ part_O, float* __restrict__ part_m, float* __restrict__ part_l)
{
    __shared__ unsigned short Kb[2][64][136];   // [g][pos][d]   34816 B
    __shared__ unsigned short Vt[2][128][76];   // [g][d][slot]  38912 B
    __shared__ unsigned short Pw[8][16 * 76];   // per-wave P    19456 B

    const int t = threadIdx.x;
    const int w = t >> 6, lane = t & 63, l15 = lane & 15, quad = lane >> 4;
    const int gsel = w >> 2;          // which head of the pair
    const int rep  = w & 3;           // rep-head within group
    const int blk = blockIdx.x;
    const int b = blk >> 5, gg = (blk >> 3) & 3, c = blk & 7;
    const int g = gg * 2 + gsel;

    const int p0 = t >> 6;            // = w (uniform per wave)
    const int q4 = t & 63;            // float4 index within [2g][128d] row
    const int gl = q4 >> 5;           // g-half this thread stages
    const int d0 = (q4 & 31) << 2;    // d offset

    bf16x8 qhf[4], qlf[4];
    {
        size_t base = (size_t)(b * 16 + l15) * DIM + (g * 4 + rep) * HD + quad * 8;
        #pragma unroll
        for (int kt = 0; kt < 4; ++kt) {
            qhf[kt] = ldsfrag(qhp + base + kt * 32);
            qlf[kt] = ldsfrag(qlp + base + kt * 32);
        }
    }

    float m_run[4], l_run[4];
    f32x4 oacc[8];
    #pragma unroll
    for (int r = 0; r < 4; ++r) { m_run[r] = -INFINITY; l_run[r] = 0.f; }
    #pragma unroll
    for (int d = 0; d < 8; ++d) oacc[d] = (f32x4){0.f, 0.f, 0.f, 0.f};

    float4 kreg[8], vreg[8];          // single buffer, static indices only (rule #20)
    auto LOADKV = [&](int it) {       // it = 64-pos tile index, 0..7
        #pragma unroll
        for (int i = 0; i < 8; ++i) {
            int pos = p0 + i * 8;
            int pg = c * CHUNK + it * 64 + pos;
            const float *ksrc, *vsrc;
            if (pg >= START_POS) {
                size_t off = (size_t)(b * 16 + pg - START_POS) * (NKVH * HD) + gg * 256 + q4 * 4;
                ksrc = knew + off; vsrc = vnew + off;
            } else {
                size_t off = ((size_t)(b * MAX_SEQ + pg) * NKVH) * HD + gg * 256 + q4 * 4;
                ksrc = kc + off; vsrc = vc + off;
            }
            kreg[i] = *(const float4*)ksrc;
            vreg[i] = *(const float4*)vsrc;
        }
    };

    unsigned short* phw = Pw[w];
    const int slotbase = (l15 & 7) * 8 + (l15 >> 3);   // + 2*nt for S-col nt*16+l15

    LOADKV(0);
    for (int it = 0; it < 8; ++it) {             // 8 iters x 64 pos = 512 pos
        __syncthreads();
        // K: [g][pos][d], b64 writes; wave's lanes cover one pos-pair-row contiguously
        #pragma unroll
        for (int i = 0; i < 8; ++i) {
            int pos = p0 + i * 8;
            ushort4 k4 = make_ushort4(f2bf(kreg[i].x), f2bf(kreg[i].y),
                                      f2bf(kreg[i].z), f2bf(kreg[i].w));
            *(ushort4*)&Kb[gl][pos][d0] = k4;
        }
        // V: register-gather transpose. Thread holds pos = p0+8i (i=0..7) at fixed (gl,d0).
        // slot(pos) = (pos&7)*8 + (pos>>3) => thread's 8 pos -> slots p0*8..p0*8+7.
        #pragma unroll
        for (int j = 0; j < 4; ++j) {
            ushort4 vlo = make_ushort4(f2bf(VCOMP(vreg[0], j)), f2bf(VCOMP(vreg[1], j)),
                                       f2bf(VCOMP(vreg[2], j)), f2bf(VCOMP(vreg[3], j)));
            ushort4 vhi = make_ushort4(f2bf(VCOMP(vreg[4], j)), f2bf(VCOMP(vreg[5], j)),
                                       f2bf(VCOMP(vreg[6], j)), f2bf(VCOMP(vreg[7], j)));
            *(ushort4*)&Vt[gl][d0 + j][p0 * 8]     = vlo;
            *(ushort4*)&Vt[gl][d0 + j][p0 * 8 + 4] = vhi;
        }
        __syncthreads();
        if (it + 1 < 8) LOADKV(it + 1);          // in flight across the whole compute phase

        // S = Q K^T (4 n-tiles x 4 k-steps x {hi,lo})
        f32x4 sacc[4];
        #pragma unroll
        for (int nt = 0; nt < 4; ++nt) sacc[nt] = (f32x4){0.f,0.f,0.f,0.f};
        #pragma unroll
        for (int nt = 0; nt < 4; ++nt)
            #pragma unroll
            for (int kt = 0; kt < 4; ++kt) {
                bf16x8 bh = ldsfrag(&Kb[gsel][nt*16 + l15][kt*32 + quad*8]);
                sacc[nt] = MFMA16(qhf[kt], bh, sacc[nt]);
                sacc[nt] = MFMA16(qlf[kt], bh, sacc[nt]);
            }

        // online softmax over 64 positions; q-row = quad*4+r across the quad's 16 lanes
        float e0[4], e1[4], e2[4], e3[4], alpha[4];
        #pragma unroll
        for (int r = 0; r < 4; ++r) {
            float s0 = sacc[0][r] * ATT_SCALE;
            float s1 = sacc[1][r] * ATT_SCALE;
            float s2 = sacc[2][r] * ATT_SCALE;
            float s3 = sacc[3][r] * ATT_SCALE;
            float mx = fmaxf(fmaxf(s0, s1), fmaxf(s2, s3));
            mx = fmaxf(mx, __shfl_xor(mx, 1));
            mx = fmaxf(mx, __shfl_xor(mx, 2));
            mx = fmaxf(mx, __shfl_xor(mx, 4));
            mx = fmaxf(mx, __shfl_xor(mx, 8));
            float mnew = fmaxf(m_run[r], mx);
            alpha[r] = __expf(m_run[r] - mnew);
            e0[r] = __expf(s0 - mnew);
            e1[r] = __expf(s1 - mnew);
            e2[r] = __expf(s2 - mnew);
            e3[r] = __expf(s3 - mnew);
            float sum = (e0[r] + e1[r]) + (e2[r] + e3[r]);
            sum += __shfl_xor(sum, 1);
            sum += __shfl_xor(sum, 2);
            sum += __shfl_xor(sum, 4);
            sum += __shfl_xor(sum, 8);
            l_run[r] = l_run[r] * alpha[r] + sum;
            m_run[r] = mnew;
        }
        #pragma unroll
        for (int d = 0; d < 8; ++d)
            #pragma unroll
            for (int r = 0; r < 4; ++r) oacc[d][r] *= alpha[r];

        // P -> per-wave LDS at permuted slots: slot = slotbase + 2*nt
        #pragma unroll
        for (int r = 0; r < 4; ++r) {
            unsigned short* pr = phw + (quad*4 + r) * 76 + slotbase;
            pr[0] = f2bf(e0[r]);
            pr[2] = f2bf(e1[r]);
            pr[4] = f2bf(e2[r]);
            pr[6] = f2bf(e3[r]);
        }
        bf16x8 pa0 = ldsfrag2(phw + l15 * 76 + quad * 8);
        bf16x8 pa1 = ldsfrag2(phw + l15 * 76 + 32 + quad * 8);

        // O += P V (8 d-tiles x 2 k-steps over 64 slots)
        #pragma unroll
        for (int dt = 0; dt < 8; ++dt) {
            bf16x8 vb0 = ldsfrag2(&Vt[gsel][dt*16 + l15][quad * 8]);
            oacc[dt] = MFMA16(pa0, vb0, oacc[dt]);
            bf16x8 vb1 = ldsfrag2(&Vt[gsel][dt*16 + l15][32 + quad * 8]);
            oacc[dt] = MFMA16(pa1, vb1, oacc[dt]);
        }
    }

    // each wave owns its (g, rep) head over the full chunk: write partials directly
    const size_t obase = (size_t)((b * 8 + g) * 8 + c) * 64 + rep * 16 + quad * 4;
    #pragma unroll
    for (int dt = 0; dt < 8; ++dt)
        #pragma unroll
        for (int r = 0; r < 4; ++r)
            part_O[(obase + r) * HD + dt * 16 + l15] = oacc[dt][r];
    if (l15 == 0) {
        #pragma unroll
        for (int r = 0; r < 4; ++r) {
            part_m[obase + r] = m_run[r];
            part_l[obase + r] = l_run[r];
        }
    }
}

__global__ __launch_bounds__(128) void attn_combine_kernel(
    const float* __restrict__ part_O, const float* __restrict__ part_m,
    const float* __restrict__ part_l, unsigned short* __restrict__ ah,
    unsigned short* __restrict__ al)
{
    int bid = blockIdx.x;          // (b*8+g)*64 + row
    int d = threadIdx.x;
    int bg = bid >> 6;
    int row = bid & 63;
    float mc[NCHUNK], lc[NCHUNK];
    float M = -INFINITY;
    #pragma unroll
    for (int cc = 0; cc < NCHUNK; ++cc) {
        mc[cc] = part_m[(bg * NCHUNK + cc) * 64 + row];
        lc[cc] = part_l[(bg * NCHUNK + cc) * 64 + row];
        M = fmaxf(M, mc[cc]);
    }
    float L = 0.f, acc = 0.f;
    #pragma unroll
    for (int cc = 0; cc < NCHUNK; ++cc) {
        float wgt = __expf(mc[cc] - M);
        L += lc[cc] * wgt;
        acc += part_O[((size_t)(bg * NCHUNK + cc) * 64 + row) * HD + d] * wgt;
    }
    int b = bg >> 3, g = bg & 7;
    int r = row >> 4, qp = row & 15;
    float v = acc / L;
    unsigned short h, l; splitbf(v, h, l);
    size_t idx = (size_t)(b * 16 + qp) * DIM + (g * 4 + r) * HD + d;
    ah[idx] = h; al[idx] = l;
}

extern "C" void kernel_launch(void* const* d_in, const int* in_sizes, int n_in,
                              void* d_out, int out_size, void* d_ws, size_t ws_size,
                              hipStream_t stream)
{
    const float* x  = (const float*)d_in[0];
    const float* kc = (const float*)d_in[1];
    const float* vc = (const float*)d_in[2];
    const float* Wq = (const float*)d_in[3];
    const float* bq = (const float*)d_in[4];
    const float* Wk = (const float*)d_in[5];
    const float* bk = (const float*)d_in[6];
    const float* Wv = (const float*)d_in[7];
    const float* bv = (const float*)d_in[8];
    const float* Wo = (const float*)d_in[9];
    const float* bo = (const float*)d_in[10];
    float* out = (float*)d_out;
    float* ws  = (float*)d_ws;

    unsigned short* xh = (unsigned short*)(ws + WS_XH);
    unsigned short* xl = (unsigned short*)(ws + WS_XL);
    unsigned short* qh = (unsigned short*)(ws + WS_QH);
    unsigned short* ql = (unsigned short*)(ws + WS_QL);
    unsigned short* ath = (unsigned short*)(ws + WS_ATH);
    unsigned short* atl = (unsigned short*)(ws + WS_ATL);

    split_x_kernel<<<512, 256, 0, stream>>>(x, xh, xl, 131072);
    qkv_gemm_direct_kernel<<<dim3(48, 4), 256, 0, stream>>>(
        xh, xl, Wq, Wk, Wv, bq, bk, bv, qh, ql, ws + WS_KNEW, ws + WS_VNEW);
    attn_partial7_kernel<<<256, 512, 0, stream>>>(qh, ql, kc, vc,
                                                  ws + WS_KNEW, ws + WS_VNEW,
                                                  ws + WS_PARTO, ws + WS_PM, ws + WS_PL);
    attn_combine_kernel<<<4096, 128, 0, stream>>>(ws + WS_PARTO, ws + WS_PM,
                                                  ws + WS_PL, ath, atl);
    oproj_gemm_direct_kernel<<<dim3(32, 4), 256, 0, stream>>>(
        ath, atl, Wo, bo, out);
}